// Round 6
// baseline (473.710 us; speedup 1.0000x reference)
//
#include <hip/hip_runtime.h>
#include <cstddef>

#define HD 8
#define C2 16
#define HH 28
#define WW 28
#define BB 16
#define SP (HH*WW)           // 784
#define FEAT (HD*SP)         // 6272
#define FEAT2 (C2*SP)        // 12544

#define TILE_ROWS 2
#define NT (HH/TILE_ROWS)    // 14
#define NBLK (BB*NT)         // 224 blocks, one per (batch, row-tile)

__device__ __forceinline__ float sigf(float x) { return 1.0f / (1.0f + expf(-x)); }

struct Smem {
    float gw[C2*C2*9];                 // current node's gate weights
    float cw[HD*C2*9];                 // current node's cand weights
    float gb[C2];
    float cb[HD];
    float icw[HD*3*9];
    float icb[HD];
    float x0t[HD][TILE_ROWS+4][32];    // input-conv tile, rows r0-2..r0+3, cols -2..29
    float comb[C2][TILE_ROWS+4][32];
    union {
        float cin[C2][TILE_ROWS+2][32];
        float s_in[3][TILE_ROWS+6][36]; // raw input tile rows r0-3..r0+4, cols -3..32
    } u;
    int flags[2];
};

// Grid barrier, decontended: arrival = release-store into a private 64B line;
// block 0's threads poll one line each, then store the epoch into per-block
// private release lines. s_sleep keeps poll traffic low.
__device__ __forceinline__ void gbar(unsigned* arrive, unsigned* release,
                                     int blk, unsigned ep) {
    __syncthreads();
    __threadfence();   // publish this block's global writes (L2 writeback)
    if (threadIdx.x == 0)
        __hip_atomic_store(&arrive[(size_t)blk * 16], ep,
                           __ATOMIC_RELEASE, __HIP_MEMORY_SCOPE_AGENT);
    if (blk == 0) {
        int t = threadIdx.x;
        if (t < NBLK) {
            while (__hip_atomic_load(&arrive[(size_t)t * 16],
                                     __ATOMIC_RELAXED, __HIP_MEMORY_SCOPE_AGENT) < ep)
                __builtin_amdgcn_s_sleep(32);
        }
        __syncthreads();
        if (t < NBLK)
            __hip_atomic_store(&release[(size_t)t * 16], ep,
                               __ATOMIC_RELEASE, __HIP_MEMORY_SCOPE_AGENT);
    } else {
        if (threadIdx.x == 0) {
            while (__hip_atomic_load(&release[(size_t)blk * 16],
                                     __ATOMIC_RELAXED, __HIP_MEMORY_SCOPE_AGENT) < ep)
                __builtin_amdgcn_s_sleep(32);
        }
    }
    __threadfence();   // invalidate stale cached lines before reading peers' data
    __syncthreads();
}

// One ConvGRU cell for tile (bi, r0). Weights must already be in sm.gw/cw/gb/cb.
// x source: if x_lds, read sm.x0t (xscale applied); else global x (or zeros if null).
__device__ void gru_cell_dev(Smem& sm, int tid, int bi, int r0,
                             const float* x, bool x_lds, float xscale,
                             const float* h,
                             const float* td, const float* td_bias, bool use_bias,
                             float* hout, int* out_flag, int* flags) {
    // Phase A1: combined = concat([xscale*x, h]) * sigmoid(td), zero-padded tile
    for (int i = tid; i < C2*(TILE_ROWS+4)*32; i += 256) {
        int cidx = i & 31;
        int ridx = (i >> 5) % (TILE_ROWS+4);
        int c    = i / ((TILE_ROWS+4)*32);
        int row = r0 - 2 + ridx;
        int col = cidx - 2;
        float v = 0.0f;
        if (row >= 0 && row < HH && col >= 0 && col < WW) {
            float base = 0.0f;
            if (c < HD) {
                if (x_lds)      base = xscale * sm.x0t[c][ridx][cidx];
                else if (x)     base = xscale * x[((size_t)bi*HD + c)*SP + row*WW + col];
            } else {
                if (h)          base = h[((size_t)bi*HD + (c-HD))*SP + row*WW + col];
            }
            if (base != 0.0f) {
                float tdv = use_bias ? td_bias[c*SP + row*WW + col]
                                     : td[((size_t)bi*C2 + c)*SP + row*WW + col];
                v = base * sigf(tdv);
            }
        }
        sm.comb[c][ridx][cidx] = v;
    }
    // Phase A2: cand-input channels 0..7 = xscale * x (unmodulated)
    for (int i = tid; i < HD*(TILE_ROWS+2)*32; i += 256) {
        int cidx = i & 31;
        int ridx = (i >> 5) % (TILE_ROWS+2);
        int c    = i / ((TILE_ROWS+2)*32);
        int row = r0 - 1 + ridx;
        int col = cidx - 1;
        float v = 0.0f;
        if (row >= 0 && row < HH && col >= 0 && col < WW) {
            if (x_lds)      v = xscale * sm.x0t[c][ridx+1][cidx+1];
            else if (x)     v = xscale * x[((size_t)bi*HD + c)*SP + row*WW + col];
        }
        sm.u.cin[c][ridx][cidx] = v;
    }
    __syncthreads();

    // Phase B: r gates at rows r0-1..r0+2 (4) x cols -1..28 (30) x 8ch (2 halves)
    if (tid < (TILE_ROWS+2)*30*2) {
        int half  = tid & 1;
        int pos   = tid >> 1;
        int ridx2 = pos / 30;
        int cp    = pos % 30;
        float acc0 = sm.gb[half*4+0], acc1 = sm.gb[half*4+1],
              acc2 = sm.gb[half*4+2], acc3 = sm.gb[half*4+3];
        for (int ic = 0; ic < C2; ++ic) {
            float cv[3][3];
            #pragma unroll
            for (int dy = 0; dy < 3; ++dy)
                #pragma unroll
                for (int dx = 0; dx < 3; ++dx)
                    cv[dy][dx] = sm.comb[ic][ridx2+dy][cp+dx];
            const float* wp = &sm.gw[(half*4*C2 + ic)*9];
            #pragma unroll
            for (int dy = 0; dy < 3; ++dy)
                #pragma unroll
                for (int dx = 0; dx < 3; ++dx) {
                    float cvv = cv[dy][dx];
                    acc0 += cvv * wp[0*C2*9 + dy*3+dx];
                    acc1 += cvv * wp[1*C2*9 + dy*3+dx];
                    acc2 += cvv * wp[2*C2*9 + dy*3+dx];
                    acc3 += cvv * wp[3*C2*9 + dy*3+dx];
                }
        }
        int row = r0 - 1 + ridx2;
        int col = cp - 1;
        bool inb = (row >= 0 && row < HH && col >= 0 && col < WW);
        float av[4] = {acc0, acc1, acc2, acc3};
        #pragma unroll
        for (int o = 0; o < 4; ++o) {
            int ch = half*4 + o;
            float hv = 0.0f;
            if (h && inb) hv = h[((size_t)bi*HD + ch)*SP + row*WW + col];
            sm.u.cin[HD + ch][ridx2][cp] = sigf(av[o]) * hv;
        }
    }
    __syncthreads();

    // Phase C: u gate + cand conv + blend
    bool nz = false;
    for (int item = tid; item < TILE_ROWS*WW*HD; item += 256) {
        int c   = item / (TILE_ROWS*WW);
        int rem = item % (TILE_ROWS*WW);
        int rr  = rem / WW;
        int col = rem % WW;
        float uacc = sm.gb[HD + c];
        float cacc = sm.cb[c];
        for (int ic = 0; ic < C2; ++ic) {
            const float* uwp = &sm.gw[((HD + c)*C2 + ic)*9];
            const float* cwp = &sm.cw[(c*C2 + ic)*9];
            #pragma unroll
            for (int dy = 0; dy < 3; ++dy)
                #pragma unroll
                for (int dx = 0; dx < 3; ++dx) {
                    uacc += sm.comb[ic][rr+1+dy][col+1+dx] * uwp[dy*3+dx];
                    cacc += sm.u.cin[ic][rr+dy][col+dx]    * cwp[dy*3+dx];
                }
        }
        float u    = sigf(uacc);
        float cand = tanhf(cacc);
        int row = r0 + rr;
        size_t oidx = ((size_t)bi*HD + c)*SP + row*WW + col;
        float hv = h ? h[oidx] : 0.0f;
        float outv = (1.0f - u) * hv + u * cand;
        hout[oidx] = outv;
        nz |= (outv != 0.0f);
    }
    if (out_flag) {
        unsigned long long m = __ballot(nz);
        if ((tid & 63) == 0 && m) atomicOr(out_flag, 1);
    }
    __syncthreads();   // LDS safe for reuse
}

__global__ void init_kernel(unsigned* arrive, unsigned* release, int* flags) {
    int t = threadIdx.x;
    for (int i = t; i < NBLK*16; i += 256) { arrive[i] = 0u; release[i] = 0u; }
    if (t == 0) { flags[0] = 0; flags[1] = 0; }
}

// (256,1): minimum 1 wave/EU -> allocator may use up to ~512 VGPRs.
// Grid is 224 blocks <= 256 CUs, so each CU hosts one block (4 waves on
// 4 SIMDs) regardless -- lifting the VGPR cap costs zero occupancy and
// (theory) eliminates the scratch spill traffic that dominates runtime.
__global__ __launch_bounds__(256, 1)
void mega_kernel(const float* __restrict__ input_tensor, const float* __restrict__ topdown,
                 const float* __restrict__ icw, const float* __restrict__ icb,
                 const float* __restrict__ gates_w, const float* __restrict__ gates_b,
                 const float* __restrict__ can_w, const float* __restrict__ can_b,
                 const float* __restrict__ td_w0, const float* __restrict__ td_b0,
                 const float* __restrict__ td_w1, const float* __restrict__ td_b1,
                 const float* __restrict__ fc1_w, const float* __restrict__ fc1_b,
                 const float* __restrict__ fc2_w, const float* __restrict__ fc2_b,
                 float* __restrict__ out,
                 float* __restrict__ h00, float* __restrict__ h01, float* __restrict__ h02,
                 float* __restrict__ h10, float* __restrict__ h11, float* __restrict__ h12,
                 float* __restrict__ td0, float* __restrict__ td1,
                 float* __restrict__ p1,
                 int* flags, unsigned* arrive, unsigned* release)
{
    const int tid = threadIdx.x;
    const int blk = blockIdx.x;
    const int bi  = blk / NT;
    const int r0  = (blk % NT) * TILE_ROWS;

    __shared__ Smem sm;
    unsigned ep = 0;

    // ---- Phase S0 (no prior barrier): node-0 weights + local input-conv tile ----
    for (int i = tid; i < C2*C2*9; i += 256) sm.gw[i] = gates_w[i];
    for (int i = tid; i < HD*C2*9; i += 256) sm.cw[i] = can_w[i];
    if (tid < C2) sm.gb[tid] = gates_b[tid];
    if (tid < HD) sm.cb[tid] = can_b[tid];
    for (int i = tid; i < HD*3*9; i += 256) sm.icw[i] = icw[i];
    if (tid < HD) sm.icb[tid] = icb[tid];

    // raw input tile rows r0-3..r0+4, cols -3..32 (zero-padded)
    for (int i = tid; i < 3*(TILE_ROWS+6)*36; i += 256) {
        int ci = i % 36;
        int ri = (i / 36) % (TILE_ROWS+6);
        int c  = i / ((TILE_ROWS+6)*36);
        int row = r0 - 3 + ri;
        int col = ci - 3;
        float v = 0.0f;
        if (row >= 0 && row < HH && col >= 0 && col < WW)
            v = input_tensor[((size_t)bi*3 + c)*SP + row*WW + col];
        sm.u.s_in[c][ri][ci] = v;
    }
    __syncthreads();

    // x0 tile with halo: rows r0-2..r0+3, cols -2..29
    for (int i = tid; i < HD*(TILE_ROWS+4)*32; i += 256) {
        int ci = i & 31;
        int ri = (i >> 5) % (TILE_ROWS+4);
        int oc = i / ((TILE_ROWS+4)*32);
        int row = r0 - 2 + ri;
        int col = ci - 2;
        float v = 0.0f;
        if (row >= 0 && row < HH && col >= 0 && col < WW) {
            float acc = sm.icb[oc];
            for (int ic = 0; ic < 3; ++ic)
                #pragma unroll
                for (int dy = 0; dy < 3; ++dy)
                    #pragma unroll
                    for (int dx = 0; dx < 3; ++dx)
                        acc += sm.u.s_in[ic][ri+dy][ci+dx]
                             * sm.icw[((oc*3 + ic)*3 + dy)*3 + dx];
            v = acc;
        }
        sm.x0t[oc][ri][ci] = v;
    }
    __syncthreads();

    // Sweep-0 node 0: x = x0 tile, h = 0, td = bias-reshape
    gru_cell_dev(sm, tid, bi, r0, nullptr, true, 1.0f, nullptr,
                 nullptr, td_b0, true, h00, nullptr, flags);

    // Sweep-0 nodes 1,2: x=0, h=0 => comb==0 regardless of td, so the cell
    // reduces exactly to per-channel constants sig(gb_u[c]) * tanh(cb[c]).
    {
        bool nz1 = false, nz2 = false;
        for (int item = tid; item < TILE_ROWS*WW*HD; item += 256) {
            int c   = item / (TILE_ROWS*WW);
            int rem = item % (TILE_ROWS*WW);
            int rr  = rem / WW;
            int col = rem % WW;
            float v1 = sigf(gates_b[C2 + HD + c])   * tanhf(can_b[HD + c]);
            float v2 = sigf(gates_b[2*C2 + HD + c]) * tanhf(can_b[2*HD + c]);
            size_t oidx = ((size_t)bi*HD + c)*SP + (r0 + rr)*WW + col;
            h01[oidx] = v1;
            h02[oidx] = v2;
            nz1 |= (v1 != 0.0f);
            nz2 |= (v2 != 0.0f);
        }
        unsigned long long m1 = __ballot(nz1), m2 = __ballot(nz2);
        if ((tid & 63) == 0) {
            if (m1) atomicOr(&flags[0], 1);
            if (m2) atomicOr(&flags[1], 1);
        }
    }
    gbar(arrive, release, blk, ++ep);

    // flags are now globally consistent -> uniform branch across the grid
    if (tid == 0) {
        sm.flags[0] = __hip_atomic_load(&flags[0], __ATOMIC_RELAXED, __HIP_MEMORY_SCOPE_AGENT);
        sm.flags[1] = __hip_atomic_load(&flags[1], __ATOMIC_RELAXED, __HIP_MEMORY_SCOPE_AGENT);
    }
    __syncthreads();
    const int f0 = sm.flags[0], f1 = sm.flags[1];

    // ---- td projections (dead on this data; kept for generality) ----
    if (f0 | f1) {
        int gtid = blk*256 + tid;
        if (gtid < 2*FEAT2) {
            int nn = gtid / FEAT2;
            int j  = gtid % FEAT2;
            if (nn ? f1 : f0) {
                const float* hin  = nn ? h02 : h01;
                const float* w    = nn ? td_w1 : td_w0;
                const float* bias = nn ? td_b1 : td_b0;
                float* o          = nn ? td1 : td0;
                float scale       = nn ? 0.5f : 0.6f;
                const float* wr = w + (size_t)j * FEAT;
                // Two passes of 8 batches each: halves peak register demand.
                for (int hq = 0; hq < 2; ++hq) {
                    float acc[8];
                    #pragma unroll
                    for (int q = 0; q < 8; ++q) acc[q] = 0.0f;
                    const float* hb = hin + (size_t)(hq*8)*FEAT;
                    for (int k = 0; k < FEAT; ++k) {
                        float wv = wr[k];
                        #pragma unroll
                        for (int q = 0; q < 8; ++q)
                            acc[q] += (scale * hb[(size_t)q*FEAT + k]) * wv;
                    }
                    #pragma unroll
                    for (int q = 0; q < 8; ++q)
                        o[(size_t)(hq*8+q)*FEAT2 + j] = acc[q] + bias[j];
                }
            }
        }
        gbar(arrive, release, blk, ++ep);
    }

    // ---- Sweep 1, node 0 (node-0 weights still resident in LDS) ----
    gru_cell_dev(sm, tid, bi, r0, nullptr, true, 1.0f, h00,
                 td0, td_b0, f0 == 0, h10, nullptr, flags);
    gbar(arrive, release, blk, ++ep);

    // ---- Sweep 1, node 1 ----
    for (int i = tid; i < C2*C2*9; i += 256) sm.gw[i] = gates_w[C2*C2*9 + i];
    for (int i = tid; i < HD*C2*9; i += 256) sm.cw[i] = can_w[HD*C2*9 + i];
    if (tid < C2) sm.gb[tid] = gates_b[C2 + tid];
    if (tid < HD) sm.cb[tid] = can_b[HD + tid];
    __syncthreads();
    gru_cell_dev(sm, tid, bi, r0, h10, false, 0.8f, h01,
                 td1, td_b1, f1 == 0, h11, nullptr, flags);
    gbar(arrive, release, blk, ++ep);

    // ---- Sweep 1, node 2 ----
    for (int i = tid; i < C2*C2*9; i += 256) sm.gw[i] = gates_w[2*C2*C2*9 + i];
    for (int i = tid; i < HD*C2*9; i += 256) sm.cw[i] = can_w[2*HD*C2*9 + i];
    if (tid < C2) sm.gb[tid] = gates_b[2*C2 + tid];
    if (tid < HD) sm.cb[tid] = can_b[2*HD + tid];
    __syncthreads();
    gru_cell_dev(sm, tid, bi, r0, h11, false, 0.7f, h02,
                 topdown, nullptr, false, h12, nullptr, flags);
    gbar(arrive, release, blk, ++ep);

    // ---- fc1 on blocks 0..99 ----
    if (blk < 100) {
        int j    = blk;
        int wave = tid >> 6;
        int lane = tid & 63;
        float acc[4] = {0.f, 0.f, 0.f, 0.f};
        const float* wr = fc1_w + (size_t)j * FEAT;
        for (int k = lane; k < FEAT; k += 64) {
            float wv = wr[k];
            #pragma unroll
            for (int q = 0; q < 4; ++q) {
                float v = h12[(size_t)(wave*4+q)*FEAT + k];
                acc[q] += fmaxf(v, 0.0f) * wv;
            }
        }
        #pragma unroll
        for (int off = 32; off > 0; off >>= 1)
            #pragma unroll
            for (int q = 0; q < 4; ++q)
                acc[q] += __shfl_down(acc[q], off);
        if (lane == 0) {
            #pragma unroll
            for (int q = 0; q < 4; ++q)
                p1[(size_t)(wave*4+q)*100 + j] = acc[q] + fc1_b[j];
        }
    }
    gbar(arrive, release, blk, ++ep);

    // ---- fc2 on block 0 ----
    if (blk == 0 && tid < BB*10) {
        int b2 = tid / 10, j = tid % 10;
        float acc = fc2_b[j];
        for (int k = 0; k < 100; ++k)
            acc += fmaxf(p1[b2*100 + k], 0.0f) * fc2_w[j*100 + k];
        out[b2*10 + j] = acc;
    }
}

extern "C" void kernel_launch(void* const* d_in, const int* in_sizes, int n_in,
                              void* d_out, int out_size, void* d_ws, size_t ws_size,
                              hipStream_t stream) {
    const float* input_tensor = (const float*)d_in[0];
    const float* topdown      = (const float*)d_in[1];
    const float* icw  = (const float*)d_in[2];
    const float* icb  = (const float*)d_in[3];
    const float* gates_w = (const float*)d_in[4];
    const float* gates_b = (const float*)d_in[5];
    const float* can_w   = (const float*)d_in[6];
    const float* can_b   = (const float*)d_in[7];
    const float* td_w0 = (const float*)d_in[8];
    const float* td_b0 = (const float*)d_in[9];
    const float* td_w1 = (const float*)d_in[10];
    const float* td_b1 = (const float*)d_in[11];
    const float* fc1_w = (const float*)d_in[12];
    const float* fc1_b = (const float*)d_in[13];
    const float* fc2_w = (const float*)d_in[14];
    const float* fc2_b = (const float*)d_in[15];
    float* out = (float*)d_out;

    float* ws  = (float*)d_ws;
    float* h00 = ws;
    float* h01 = h00 + BB*HD*SP;
    float* h02 = h01 + BB*HD*SP;
    float* h10 = h02 + BB*HD*SP;
    float* h11 = h10 + BB*HD*SP;
    float* h12 = h11 + BB*HD*SP;
    float* td0 = h12 + BB*HD*SP;
    float* td1 = td0 + BB*C2*SP;
    float* p1  = td1 + BB*C2*SP;

    // Barrier state isolated on its own pages, far from live data.
    char* bar_base = (char*)d_ws + (8u << 20);           // ws + 8 MiB
    unsigned* arrive  = (unsigned*)bar_base;             // 224 x 64B
    unsigned* release = arrive + NBLK*16;                // 224 x 64B
    int*      flags   = (int*)(release + NBLK*16);

    init_kernel<<<1, 256, 0, stream>>>(arrive, release, flags);
    mega_kernel<<<NBLK, 256, 0, stream>>>(
        input_tensor, topdown, icw, icb, gates_w, gates_b, can_w, can_b,
        td_w0, td_b0, td_w1, td_b1, fc1_w, fc1_b, fc2_w, fc2_b, out,
        h00, h01, h02, h10, h11, h12, td0, td1, p1, flags, arrive, release);
}

// Round 7
// 338.890 us; speedup vs baseline: 1.3978x; 1.3978x over previous
//
#include <hip/hip_runtime.h>
#include <cstddef>

#define HD 8
#define C2 16
#define HH 28
#define WW 28
#define BB 16
#define SP (HH*WW)           // 784
#define FEAT (HD*SP)         // 6272
#define FEAT2 (C2*SP)        // 12544

#define TILE_ROWS 2
#define NT (HH/TILE_ROWS)    // 14
#define NBLK (BB*NT)         // 224 blocks, one per (batch, row-tile)
#define CH 6                 // max chunk rows per cell pass

// slab layout (floats), per block: private extended-halo states
#define X0_R 18   // x0  rows [r0-8, r0+9]
#define H00_R 14  // h00 rows [r0-6, r0+7]
#define H10_R 10  // h10 rows [r0-4, r0+5]
#define H11_R 6   // h11 rows [r0-2, r0+3]
#define SLAB_F (HD*32*(X0_R + H00_R + H10_R + H11_R))  // 12288 floats

__device__ __forceinline__ float sigf(float x) { return 1.0f / (1.0f + expf(-x)); }

struct SM {
    float gw[C2*C2*9];                // 2304 f  current node's gate weights (r=oc0..7, u=oc8..15)
    float cw[HD*C2*9];                // 1152 f
    float gb[C2];
    float cb[HD];
    float hc1[HD];                    // h01 per-channel constant
    float hc2[HD];                    // h02 per-channel constant
    float comb[C2][CH+4][32];         // 5120 f
    union {
        float cin[C2][CH+2][32];      // 4096 f
        float s_in[3][TILE_ROWS+18][32]; // 1920 f (raw input rows r0-9..r0+10)
    } u;
};  // ~50.9 KB

// Grid barrier (FALLBACK PATH ONLY — never executed when gate/cand biases are zero).
__device__ __forceinline__ void gbar(unsigned* arrive, unsigned* release,
                                     int blk, unsigned ep) {
    __syncthreads();
    __threadfence();
    if (threadIdx.x == 0)
        __hip_atomic_store(&arrive[(size_t)blk * 16], ep,
                           __ATOMIC_RELEASE, __HIP_MEMORY_SCOPE_AGENT);
    if (blk == 0) {
        int t = threadIdx.x;
        if (t < NBLK) {
            while (__hip_atomic_load(&arrive[(size_t)t * 16],
                                     __ATOMIC_RELAXED, __HIP_MEMORY_SCOPE_AGENT) < ep)
                __builtin_amdgcn_s_sleep(32);
        }
        __syncthreads();
        if (t < NBLK)
            __hip_atomic_store(&release[(size_t)t * 16], ep,
                               __ATOMIC_RELEASE, __HIP_MEMORY_SCOPE_AGENT);
    } else {
        if (threadIdx.x == 0) {
            while (__hip_atomic_load(&release[(size_t)blk * 16],
                                     __ATOMIC_RELAXED, __HIP_MEMORY_SCOPE_AGENT) < ep)
                __builtin_amdgcn_s_sleep(32);
        }
    }
    __threadfence();
    __syncthreads();
}

__device__ void stage_node(SM& sm, int tid, int n,
                           const float* gates_w, const float* gates_b,
                           const float* can_w, const float* can_b) {
    for (int i = tid; i < C2*C2*9; i += 256) sm.gw[i] = gates_w[n*C2*C2*9 + i];
    for (int i = tid; i < HD*C2*9; i += 256) sm.cw[i] = can_w[n*HD*C2*9 + i];
    if (tid < C2) sm.gb[tid] = gates_b[n*C2 + tid];
    if (tid < HD) sm.cb[tid] = can_b[n*HD + tid];
    // no barrier needed here: the consumer cell's first __syncthreads covers it
}

// Generic ConvGRU cell over output rows [a,b] (block-local, chunked).
// x: slab xb (layout [8][XR][32], base row xa, col=ci-2, pads 0) or null => 0.
// h: slab hb or per-channel const hc (null,null => 0).
// td: tdv = 12544-vector (c*784+row*28+col) OR tdf = per-image full td, same idx.
// out: slab ob (base row a, OR rows) or, if ob==null, final h12 global.
__device__ void cell(SM& sm, int tid, int bi, int a, int b,
                     const float* xb, int xa, int XR, float xs,
                     const float* hb, int ha, int HR, const float* hc,
                     const float* tdv, const float* tdf,
                     float* ob, int OR, float* h12g) {
    for (int ca = a; ca <= b; ca += CH) {
        const int cb2 = (ca + CH - 1 < b) ? ca + CH - 1 : b;
        const int m = cb2 - ca + 1;
        const int R1 = m + 4, R2 = m + 2;

        // comb = concat(xs*x, h) * sig(td), rows [ca-2, cb2+2]
        for (int i = tid; i < C2*R1*32; i += 256) {
            int ci = i & 31, rr = (i >> 5) % R1, c = i / (32*R1);
            int row = ca - 2 + rr, col = ci - 2;
            float v = 0.0f;
            if (row >= 0 && row < HH && col >= 0 && col < WW) {
                float base;
                if (c < HD) base = xb ? xs * xb[(c*XR + (row - xa))*32 + ci] : 0.0f;
                else        base = hb ? hb[((c-HD)*HR + (row - ha))*32 + ci]
                                      : (hc ? hc[c-HD] : 0.0f);
                float td = tdv ? tdv[c*SP + row*WW + col] : tdf[c*SP + row*WW + col];
                v = base * sigf(td);
            }
            sm.comb[c][rr][ci] = v;
        }
        // cin x-part, rows [ca-1, cb2+1]
        for (int i = tid; i < HD*R2*32; i += 256) {
            int ci = i & 31, rr = (i >> 5) % R2, c = i / (32*R2);
            int row = ca - 1 + rr, col = ci - 2;
            float v = 0.0f;
            if (row >= 0 && row < HH && col >= 0 && col < WW && xb)
                v = xs * xb[(c*XR + (row - xa))*32 + ci];
            sm.u.cin[c][rr][ci] = v;
        }
        __syncthreads();

        // r-gate * h -> cin[8+c], rows [ca-1, cb2+1], 4-oc groups
        for (int i = tid; i < 2*R2*32; i += 256) {
            int ci = i & 31, rr = (i >> 5) % R2, g = i / (32*R2);
            int row = ca - 1 + rr, col = ci - 2;
            float a0, a1, a2, a3;
            bool inb = (row >= 0 && row < HH && col >= 0 && col < WW);
            a0 = sm.gb[g*4+0]; a1 = sm.gb[g*4+1]; a2 = sm.gb[g*4+2]; a3 = sm.gb[g*4+3];
            if (inb) {
                for (int ic = 0; ic < C2; ++ic) {
                    float cv[3][3];
                    #pragma unroll
                    for (int dy = 0; dy < 3; ++dy)
                        #pragma unroll
                        for (int dx = 0; dx < 3; ++dx)
                            cv[dy][dx] = sm.comb[ic][rr+dy][ci-1+dx];
                    const float* wp = &sm.gw[(g*4*C2 + ic)*9];
                    #pragma unroll
                    for (int dy = 0; dy < 3; ++dy)
                        #pragma unroll
                        for (int dx = 0; dx < 3; ++dx) {
                            float cvv = cv[dy][dx];
                            a0 += cvv * wp[0*C2*9 + dy*3+dx];
                            a1 += cvv * wp[1*C2*9 + dy*3+dx];
                            a2 += cvv * wp[2*C2*9 + dy*3+dx];
                            a3 += cvv * wp[3*C2*9 + dy*3+dx];
                        }
                }
            }
            float av[4] = {a0, a1, a2, a3};
            #pragma unroll
            for (int o = 0; o < 4; ++o) {
                int c = g*4 + o;
                float v = 0.0f;
                if (inb) {
                    float hv = hb ? hb[(c*HR + (row - ha))*32 + ci] : (hc ? hc[c] : 0.0f);
                    v = sigf(av[o]) * hv;
                }
                sm.u.cin[HD + c][rr][ci] = v;
            }
        }
        __syncthreads();

        // u + cand + blend at rows [ca, cb2], 4-oc groups
        for (int i = tid; i < 2*m*32; i += 256) {
            int ci = i & 31, rr = (i >> 5) % m, g = i / (32*m);
            int row = ca + rr, col = ci - 2;
            bool inb = (row >= 0 && row < HH && col >= 0 && col < WW);
            float ua0 = sm.gb[HD+g*4+0], ua1 = sm.gb[HD+g*4+1],
                  ua2 = sm.gb[HD+g*4+2], ua3 = sm.gb[HD+g*4+3];
            float ca0 = sm.cb[g*4+0], ca1 = sm.cb[g*4+1],
                  ca2 = sm.cb[g*4+2], ca3 = sm.cb[g*4+3];
            if (inb) {
                for (int ic = 0; ic < C2; ++ic) {
                    const float* uwp = &sm.gw[((HD + g*4)*C2 + ic)*9];
                    const float* cwp = &sm.cw[((g*4)*C2 + ic)*9];
                    #pragma unroll
                    for (int dy = 0; dy < 3; ++dy)
                        #pragma unroll
                        for (int dx = 0; dx < 3; ++dx) {
                            float cvv = sm.comb[ic][rr+1+dy][ci-1+dx];
                            float civ = sm.u.cin[ic][rr+dy][ci-1+dx];
                            ua0 += cvv * uwp[0*C2*9 + dy*3+dx];
                            ua1 += cvv * uwp[1*C2*9 + dy*3+dx];
                            ua2 += cvv * uwp[2*C2*9 + dy*3+dx];
                            ua3 += cvv * uwp[3*C2*9 + dy*3+dx];
                            ca0 += civ * cwp[0*C2*9 + dy*3+dx];
                            ca1 += civ * cwp[1*C2*9 + dy*3+dx];
                            ca2 += civ * cwp[2*C2*9 + dy*3+dx];
                            ca3 += civ * cwp[3*C2*9 + dy*3+dx];
                        }
                }
            }
            float uav[4] = {ua0, ua1, ua2, ua3};
            float cav[4] = {ca0, ca1, ca2, ca3};
            #pragma unroll
            for (int o = 0; o < 4; ++o) {
                int c = g*4 + o;
                float outv = 0.0f;
                if (inb) {
                    float u = sigf(uav[o]);
                    float cand = tanhf(cav[o]);
                    float hv = hb ? hb[(c*HR + (row - ha))*32 + ci] : (hc ? hc[c] : 0.0f);
                    outv = (1.0f - u) * hv + u * cand;
                }
                if (ob) ob[(c*OR + (row - a))*32 + ci] = outv;
                else if (inb)
                    h12g[((size_t)bi*HD + c)*SP + row*WW + col] = outv;
            }
        }
        __syncthreads();
    }
}

__global__ void init_kernel(unsigned* arrive, unsigned* release) {
    int t = threadIdx.x;
    for (int i = t; i < NBLK*16; i += 256) { arrive[i] = 0u; release[i] = 0u; }
}

__global__ __launch_bounds__(256)
void mega_kernel(const float* __restrict__ input_tensor, const float* __restrict__ topdown,
                 const float* __restrict__ icw, const float* __restrict__ icb,
                 const float* __restrict__ gates_w, const float* __restrict__ gates_b,
                 const float* __restrict__ can_w, const float* __restrict__ can_b,
                 const float* __restrict__ td_w0, const float* __restrict__ td_b0,
                 const float* __restrict__ td_w1, const float* __restrict__ td_b1,
                 float* __restrict__ h12g, float* __restrict__ slabs,
                 float* __restrict__ td0c, float* __restrict__ td1c,
                 unsigned* arrive, unsigned* release)
{
    const int tid = threadIdx.x;
    const int blk = blockIdx.x;
    const int bi  = blk / NT;
    const int r0  = (blk % NT) * TILE_ROWS;

    __shared__ SM sm;

    float* slab = slabs + (size_t)blk * SLAB_F;
    float* x0e  = slab;
    float* h00e = x0e  + HD*X0_R*32;
    float* h10e = h00e + HD*H00_R*32;
    float* h11e = h10e + HD*H10_R*32;

    // Sweep-0 node1/2 outputs are per-channel constants (x=0, h=0 => comb=0):
    // v = sig(gb_u[c]) * tanh(cb[c]). Uniform across the whole grid.
    if (tid < HD) {
        sm.hc1[tid] = sigf(gates_b[1*C2 + HD + tid]) * tanhf(can_b[1*HD + tid]);
        sm.hc2[tid] = sigf(gates_b[2*C2 + HD + tid]) * tanhf(can_b[2*HD + tid]);
    }
    bool f0 = false, f1 = false;   // does td0/td1 need the real projection?
    for (int c = 0; c < HD; ++c) {
        f0 |= (sigf(gates_b[1*C2 + HD + c]) * tanhf(can_b[1*HD + c])) != 0.0f;
        f1 |= (sigf(gates_b[2*C2 + HD + c]) * tanhf(can_b[2*HD + c])) != 0.0f;
    }

    // ---- stage raw input tile (rows r0-9..r0+10) + input-conv weights ----
    for (int i = tid; i < 3*(TILE_ROWS+18)*32; i += 256) {
        int ci = i & 31, rr = (i >> 5) % (TILE_ROWS+18), c = i / (32*(TILE_ROWS+18));
        int row = r0 - 9 + rr, col = ci - 2;
        float v = 0.0f;
        if (row >= 0 && row < HH && col >= 0 && col < WW)
            v = input_tensor[((size_t)bi*3 + c)*SP + row*WW + col];
        sm.u.s_in[c][rr][ci] = v;
    }
    for (int i = tid; i < HD*3*9; i += 256) sm.gw[i] = icw[i];   // borrow gw area
    if (tid < HD) sm.cb[tid] = icb[tid];                         // borrow cb
    __syncthreads();

    // ---- x0e: input conv on rows [r0-8, r0+9] ----
    for (int i = tid; i < HD*X0_R*32; i += 256) {
        int ci = i & 31, rr = (i >> 5) % X0_R, oc = i / (32*X0_R);
        int row = r0 - 8 + rr, col = ci - 2;
        float v = 0.0f;
        if (row >= 0 && row < HH && col >= 0 && col < WW) {
            float acc = sm.cb[oc];
            for (int ic = 0; ic < 3; ++ic)
                #pragma unroll
                for (int dy = 0; dy < 3; ++dy)
                    #pragma unroll
                    for (int dx = 0; dx < 3; ++dx)
                        acc += sm.u.s_in[ic][rr+dy][ci-1+dx]
                             * sm.gw[((oc*3 + ic)*3 + dy)*3 + dx];
            v = acc;
        }
        x0e[(oc*X0_R + rr)*32 + ci] = v;
    }
    __syncthreads();

    // ---- h00: sweep-0 node 0 (node-0 weights; h=0; td = bias reshape) ----
    stage_node(sm, tid, 0, gates_w, gates_b, can_w, can_b);
    cell(sm, tid, bi, r0-6, r0+7,
         x0e, r0-8, X0_R, 1.0f,
         nullptr, 0, 0, nullptr,
         td_b0, nullptr,
         h00e, H00_R, nullptr);

    // ---- fallback: real td projections needed (h01/h02 constants nonzero) ----
    // td0[j] = 0.6*sum_c v1[c]*rowsum_c(w0[j]) + b0[j]  (batch-independent).
    if (f0 | f1) {
        if (f0) {
            for (int j = blk*256 + tid; j < FEAT2; j += NBLK*256) {
                float s = td_b0[j];
                const float* wr = td_w0 + (size_t)j * FEAT;
                for (int c = 0; c < HD; ++c) {
                    float hcv = sm.hc1[c];
                    if (hcv != 0.0f) {
                        float ss = 0.0f;
                        for (int p = 0; p < SP; ++p) ss += wr[c*SP + p];
                        s += 0.6f * hcv * ss;
                    }
                }
                td0c[j] = s;
            }
        }
        if (f1) {
            for (int j = blk*256 + tid; j < FEAT2; j += NBLK*256) {
                float s = td_b1[j];
                const float* wr = td_w1 + (size_t)j * FEAT;
                for (int c = 0; c < HD; ++c) {
                    float hcv = sm.hc2[c];
                    if (hcv != 0.0f) {
                        float ss = 0.0f;
                        for (int p = 0; p < SP; ++p) ss += wr[c*SP + p];
                        s += 0.5f * hcv * ss;
                    }
                }
                td1c[j] = s;
            }
        }
        gbar(arrive, release, blk, 1u);   // uniform branch: all blocks take it
    }
    const float* td0v = f0 ? td0c : td_b0;
    const float* td1v = f1 ? td1c : td_b1;

    // ---- h10: sweep-1 node 0 (node-0 weights still resident) ----
    cell(sm, tid, bi, r0-4, r0+5,
         x0e, r0-8, X0_R, 1.0f,
         h00e, r0-6, H00_R, nullptr,
         td0v, nullptr,
         h10e, H10_R, nullptr);

    // ---- h11: sweep-1 node 1 (x = 0.8*h10, h = h01 const) ----
    stage_node(sm, tid, 1, gates_w, gates_b, can_w, can_b);
    cell(sm, tid, bi, r0-2, r0+3,
         h10e, r0-4, H10_R, 0.8f,
         nullptr, 0, 0, sm.hc1,
         td1v, nullptr,
         h11e, H11_R, nullptr);

    // ---- h12: sweep-1 node 2 (x = 0.7*h11, h = h02 const, td = external) ----
    stage_node(sm, tid, 2, gates_w, gates_b, can_w, can_b);
    cell(sm, tid, bi, r0, r0+1,
         h11e, r0-2, H11_R, 0.7f,
         nullptr, 0, 0, sm.hc2,
         nullptr, topdown + (size_t)bi*FEAT2,
         nullptr, 0, h12g);
}

__global__ __launch_bounds__(256)
void fc1_kernel(const float* __restrict__ in, const float* __restrict__ w,
                const float* __restrict__ b, float* __restrict__ out) {
    int j    = blockIdx.x;          // 0..99
    int wave = threadIdx.x >> 6;
    int lane = threadIdx.x & 63;
    float acc[4] = {0.f, 0.f, 0.f, 0.f};
    const float* wr = w + (size_t)j * FEAT;
    for (int k = lane; k < FEAT; k += 64) {
        float wv = wr[k];
        #pragma unroll
        for (int q = 0; q < 4; ++q) {
            float v = in[(size_t)(wave*4+q)*FEAT + k];
            acc[q] += fmaxf(v, 0.0f) * wv;
        }
    }
    #pragma unroll
    for (int off = 32; off > 0; off >>= 1)
        #pragma unroll
        for (int q = 0; q < 4; ++q)
            acc[q] += __shfl_down(acc[q], off);
    if (lane == 0) {
        #pragma unroll
        for (int q = 0; q < 4; ++q)
            out[(size_t)(wave*4+q)*100 + j] = acc[q] + b[j];
    }
}

__global__ __launch_bounds__(256)
void fc2_kernel(const float* __restrict__ p1, const float* __restrict__ w,
                const float* __restrict__ b, float* __restrict__ out) {
    int t = threadIdx.x;
    if (t >= BB*10) return;
    int bi = t / 10, j = t % 10;
    float acc = b[j];
    for (int k = 0; k < 100; ++k)
        acc += fmaxf(p1[bi*100 + k], 0.0f) * w[j*100 + k];
    out[bi*10 + j] = acc;
}

extern "C" void kernel_launch(void* const* d_in, const int* in_sizes, int n_in,
                              void* d_out, int out_size, void* d_ws, size_t ws_size,
                              hipStream_t stream) {
    const float* input_tensor = (const float*)d_in[0];
    const float* topdown      = (const float*)d_in[1];
    const float* icw  = (const float*)d_in[2];
    const float* icb  = (const float*)d_in[3];
    const float* gates_w = (const float*)d_in[4];
    const float* gates_b = (const float*)d_in[5];
    const float* can_w   = (const float*)d_in[6];
    const float* can_b   = (const float*)d_in[7];
    const float* td_w0 = (const float*)d_in[8];
    const float* td_b0 = (const float*)d_in[9];
    const float* td_w1 = (const float*)d_in[10];
    const float* td_b1 = (const float*)d_in[11];
    const float* fc1_w = (const float*)d_in[12];
    const float* fc1_b = (const float*)d_in[13];
    const float* fc2_w = (const float*)d_in[14];
    const float* fc2_b = (const float*)d_in[15];
    float* out = (float*)d_out;

    float* ws   = (float*)d_ws;
    float* h12g = ws;                       // 100352 f
    float* p1   = h12g + BB*HD*SP;          // 1600 f
    float* td0c = p1 + BB*100;              // 12544 f
    float* td1c = td0c + FEAT2;             // 12544 f
    float* slabs = (float*)((char*)d_ws + (1u << 20));       // 224 x 48 KB
    unsigned* arrive  = (unsigned*)((char*)d_ws + (16u << 20));
    unsigned* release = arrive + NBLK*16;

    init_kernel<<<1, 256, 0, stream>>>(arrive, release);
    mega_kernel<<<NBLK, 256, 0, stream>>>(
        input_tensor, topdown, icw, icb, gates_w, gates_b, can_w, can_b,
        td_w0, td_b0, td_w1, td_b1,
        h12g, slabs, td0c, td1c, arrive, release);
    fc1_kernel<<<100, 256, 0, stream>>>(h12g, fc1_w, fc1_b, p1);
    fc2_kernel<<<1, 256, 0, stream>>>(p1, fc2_w, fc2_b, out);
}

// Round 8
// 207.966 us; speedup vs baseline: 2.2778x; 1.6295x over previous
//
#include <hip/hip_runtime.h>
#include <cstddef>

#define HD 8
#define C2 16
#define HH 28
#define WW 28
#define BB 16
#define SP (HH*WW)           // 784
#define FEAT (HD*SP)         // 6272
#define FEAT2 (C2*SP)        // 12544

#define TILE_ROWS 2
#define NT (HH/TILE_ROWS)    // 14
#define NBLK (BB*NT)         // 224 blocks, one per (batch, row-tile)
#define NTHR 512             // 8 waves -> 2 waves/SIMD

// slab layout (floats), per block: private extended-halo states
#define X0_R 18   // x0  rows [r0-8, r0+9]
#define H00_R 14  // h00 rows [r0-6, r0+7]
#define H10_R 10  // h10 rows [r0-4, r0+5]
#define H11_R 6   // h11 rows [r0-2, r0+3]
#define SLAB_F (HD*32*(X0_R + H00_R + H10_R + H11_R))

__device__ __forceinline__ float sigf(float x) { return 1.0f / (1.0f + expf(-x)); }

struct SM {
    float gw[C2*C2*9];                // current node's gate weights (r=oc0..7, u=oc8..15)
    float cw[HD*C2*9];
    float gb[C2];
    float cb[HD];
    float hc1[HD];
    float hc2[HD];
    float comb[C2][6+4][32];          // max chunk M=6
    union {
        float cin[C2][6+2][32];
        float s_in[3][TILE_ROWS+18][32];
    } u;
};  // ~51 KB

// Grid barrier (FALLBACK PATH ONLY — never executed when gate/cand biases are zero).
__device__ __forceinline__ void gbar(unsigned* arrive, unsigned* release,
                                     int blk, unsigned ep) {
    __syncthreads();
    __threadfence();
    if (threadIdx.x == 0)
        __hip_atomic_store(&arrive[(size_t)blk * 16], ep,
                           __ATOMIC_RELEASE, __HIP_MEMORY_SCOPE_AGENT);
    if (blk == 0) {
        int t = threadIdx.x;
        if (t < NBLK) {
            while (__hip_atomic_load(&arrive[(size_t)t * 16],
                                     __ATOMIC_RELAXED, __HIP_MEMORY_SCOPE_AGENT) < ep)
                __builtin_amdgcn_s_sleep(32);
        }
        __syncthreads();
        if (t < NBLK)
            __hip_atomic_store(&release[(size_t)t * 16], ep,
                               __ATOMIC_RELEASE, __HIP_MEMORY_SCOPE_AGENT);
    } else {
        if (threadIdx.x == 0) {
            while (__hip_atomic_load(&release[(size_t)blk * 16],
                                     __ATOMIC_RELAXED, __HIP_MEMORY_SCOPE_AGENT) < ep)
                __builtin_amdgcn_s_sleep(32);
        }
    }
    __threadfence();
    __syncthreads();
}

__device__ void stage_node(SM& sm, int tid, int n,
                           const float* gates_w, const float* gates_b,
                           const float* can_w, const float* can_b) {
    for (int i = tid; i < C2*C2*9; i += NTHR) sm.gw[i] = gates_w[n*C2*C2*9 + i];
    for (int i = tid; i < HD*C2*9; i += NTHR) sm.cw[i] = can_w[n*HD*C2*9 + i];
    if (tid < C2) sm.gb[tid] = gates_b[n*C2 + tid];
    if (tid < HD) sm.cb[tid] = can_b[n*HD + tid];
    // consumer cell's first __syncthreads covers these writes
}

// One ConvGRU chunk: output rows [ca, ca+M-1]. M is COMPILE-TIME (cheap idx math).
// x: slab xb ([8][XR][32], base row xa, col=ci-2, halo=0) or null => 0.
// h: slab hb ([8][HR][32], base ha) or per-channel const hc (both null => 0).
// td: tdv = 12544 vec (c*784+row*28+col) or tdf (same layout, per-image).
// out: slab ob (base obase, OR rows) or, if null, global h12g.
template<int M>
__device__ void cell_chunk(SM& sm, int tid, int bi, int ca,
                           const float* xb, int xa, int XR, float xs,
                           const float* hb, int ha, int HR, const float* hc,
                           const float* tdv, const float* tdf,
                           float* ob, int obase, int OR, float* h12g) {
    constexpr int R1 = M + 4, R2 = M + 2;

    // A1: comb = concat(xs*x, h) * sig(td), rows [ca-2, ca+M+1]
    for (int i = tid; i < C2*R1*32; i += NTHR) {
        int ci = i & 31, rr = (i >> 5) % R1, c = i / (32*R1);
        int row = ca - 2 + rr, col = ci - 2;
        float v = 0.0f;
        if (row >= 0 && row < HH && col >= 0 && col < WW) {
            float base;
            if (c < HD) base = xb ? xs * xb[(c*XR + (row - xa))*32 + ci] : 0.0f;
            else        base = hb ? hb[((c-HD)*HR + (row - ha))*32 + ci]
                                  : (hc ? hc[c-HD] : 0.0f);
            float td = tdv ? tdv[c*SP + row*WW + col] : tdf[c*SP + row*WW + col];
            v = base * sigf(td);
        }
        sm.comb[c][rr][ci] = v;
    }
    // A2: cin x-part, rows [ca-1, ca+M]
    for (int i = tid; i < HD*R2*32; i += NTHR) {
        int ci = i & 31, rr = (i >> 5) % R2, c = i / (32*R2);
        int row = ca - 1 + rr, col = ci - 2;
        float v = 0.0f;
        if (row >= 0 && row < HH && col >= 0 && col < WW && xb)
            v = xs * xb[(c*XR + (row - xa))*32 + ci];
        sm.u.cin[c][rr][ci] = v;
    }
    __syncthreads();

    // B: r-gate * h -> cin[8+c], rows [ca-1, ca+M], 4-oc groups (items <= 512)
    for (int i = tid; i < 2*R2*32; i += NTHR) {
        int ci = i & 31, rr = (i >> 5) % R2, g = i / (32*R2);
        int row = ca - 1 + rr, col = ci - 2;
        bool inb = (row >= 0 && row < HH && col >= 0 && col < WW);
        float a0 = sm.gb[g*4+0], a1 = sm.gb[g*4+1],
              a2 = sm.gb[g*4+2], a3 = sm.gb[g*4+3];
        if (inb) {
            for (int ic = 0; ic < C2; ++ic) {
                float cv[3][3];
                #pragma unroll
                for (int dy = 0; dy < 3; ++dy)
                    #pragma unroll
                    for (int dx = 0; dx < 3; ++dx)
                        cv[dy][dx] = sm.comb[ic][rr+dy][ci-1+dx];
                const float* wp = &sm.gw[(g*4*C2 + ic)*9];
                #pragma unroll
                for (int dy = 0; dy < 3; ++dy)
                    #pragma unroll
                    for (int dx = 0; dx < 3; ++dx) {
                        float cvv = cv[dy][dx];
                        a0 += cvv * wp[0*C2*9 + dy*3+dx];
                        a1 += cvv * wp[1*C2*9 + dy*3+dx];
                        a2 += cvv * wp[2*C2*9 + dy*3+dx];
                        a3 += cvv * wp[3*C2*9 + dy*3+dx];
                    }
            }
        }
        float av[4] = {a0, a1, a2, a3};
        #pragma unroll
        for (int o = 0; o < 4; ++o) {
            int c = g*4 + o;
            float v = 0.0f;
            if (inb) {
                float hv = hb ? hb[(c*HR + (row - ha))*32 + ci] : (hc ? hc[c] : 0.0f);
                v = sigf(av[o]) * hv;
            }
            sm.u.cin[HD + c][rr][ci] = v;
        }
    }
    __syncthreads();

    // C: u + cand + blend at rows [ca, ca+M-1], 4-oc groups (items <= 384)
    for (int i = tid; i < 2*M*32; i += NTHR) {
        int ci = i & 31, rr = (i >> 5) % M, g = i / (32*M);
        int row = ca + rr, col = ci - 2;
        bool inb = (row >= 0 && row < HH && col >= 0 && col < WW);
        float ua0 = sm.gb[HD+g*4+0], ua1 = sm.gb[HD+g*4+1],
              ua2 = sm.gb[HD+g*4+2], ua3 = sm.gb[HD+g*4+3];
        float ca0 = sm.cb[g*4+0], ca1 = sm.cb[g*4+1],
              ca2 = sm.cb[g*4+2], ca3 = sm.cb[g*4+3];
        if (inb) {
            for (int ic = 0; ic < C2; ++ic) {
                const float* uwp = &sm.gw[((HD + g*4)*C2 + ic)*9];
                const float* cwp = &sm.cw[((g*4)*C2 + ic)*9];
                #pragma unroll
                for (int dy = 0; dy < 3; ++dy)
                    #pragma unroll
                    for (int dx = 0; dx < 3; ++dx) {
                        float cvv = sm.comb[ic][rr+1+dy][ci-1+dx];
                        float civ = sm.u.cin[ic][rr+dy][ci-1+dx];
                        ua0 += cvv * uwp[0*C2*9 + dy*3+dx];
                        ua1 += cvv * uwp[1*C2*9 + dy*3+dx];
                        ua2 += cvv * uwp[2*C2*9 + dy*3+dx];
                        ua3 += cvv * uwp[3*C2*9 + dy*3+dx];
                        ca0 += civ * cwp[0*C2*9 + dy*3+dx];
                        ca1 += civ * cwp[1*C2*9 + dy*3+dx];
                        ca2 += civ * cwp[2*C2*9 + dy*3+dx];
                        ca3 += civ * cwp[3*C2*9 + dy*3+dx];
                    }
            }
        }
        float uav[4] = {ua0, ua1, ua2, ua3};
        float cav[4] = {ca0, ca1, ca2, ca3};
        #pragma unroll
        for (int o = 0; o < 4; ++o) {
            int c = g*4 + o;
            float outv = 0.0f;
            if (inb) {
                float u = sigf(uav[o]);
                float cand = tanhf(cav[o]);
                float hv = hb ? hb[(c*HR + (row - ha))*32 + ci] : (hc ? hc[c] : 0.0f);
                outv = (1.0f - u) * hv + u * cand;
            }
            if (ob) ob[(c*OR + (row - obase))*32 + ci] = outv;
            else if (inb)
                h12g[((size_t)bi*HD + c)*SP + row*WW + col] = outv;
        }
    }
    __syncthreads();
}

__global__ void init_kernel(unsigned* arrive, unsigned* release) {
    int t = threadIdx.x;
    for (int i = t; i < NBLK*16; i += 256) { arrive[i] = 0u; release[i] = 0u; }
}

__global__ __launch_bounds__(NTHR)
void mega_kernel(const float* __restrict__ input_tensor, const float* __restrict__ topdown,
                 const float* __restrict__ icw, const float* __restrict__ icb,
                 const float* __restrict__ gates_w, const float* __restrict__ gates_b,
                 const float* __restrict__ can_w, const float* __restrict__ can_b,
                 const float* __restrict__ td_w0, const float* __restrict__ td_b0,
                 const float* __restrict__ td_w1, const float* __restrict__ td_b1,
                 float* __restrict__ h12g, float* __restrict__ slabs,
                 float* __restrict__ td0c, float* __restrict__ td1c,
                 unsigned* arrive, unsigned* release)
{
    const int tid = threadIdx.x;
    const int blk = blockIdx.x;
    const int bi  = blk / NT;
    const int r0  = (blk % NT) * TILE_ROWS;

    __shared__ SM sm;

    float* slab = slabs + (size_t)blk * SLAB_F;
    float* x0e  = slab;
    float* h00e = x0e  + HD*X0_R*32;
    float* h10e = h00e + HD*H00_R*32;
    float* h11e = h10e + HD*H10_R*32;

    // Sweep-0 node1/2 outputs are per-channel constants (x=0,h=0 => comb=0).
    if (tid < HD) {
        sm.hc1[tid] = sigf(gates_b[1*C2 + HD + tid]) * tanhf(can_b[1*HD + tid]);
        sm.hc2[tid] = sigf(gates_b[2*C2 + HD + tid]) * tanhf(can_b[2*HD + tid]);
    }
    bool f0 = false, f1 = false;
    for (int c = 0; c < HD; ++c) {
        f0 |= (sigf(gates_b[1*C2 + HD + c]) * tanhf(can_b[1*HD + c])) != 0.0f;
        f1 |= (sigf(gates_b[2*C2 + HD + c]) * tanhf(can_b[2*HD + c])) != 0.0f;
    }

    // ---- stage raw input tile (rows r0-9..r0+10) + input-conv weights ----
    for (int i = tid; i < 3*(TILE_ROWS+18)*32; i += NTHR) {
        int ci = i & 31, rr = (i >> 5) % (TILE_ROWS+18), c = i / (32*(TILE_ROWS+18));
        int row = r0 - 9 + rr, col = ci - 2;
        float v = 0.0f;
        if (row >= 0 && row < HH && col >= 0 && col < WW)
            v = input_tensor[((size_t)bi*3 + c)*SP + row*WW + col];
        sm.u.s_in[c][rr][ci] = v;
    }
    for (int i = tid; i < HD*3*9; i += NTHR) sm.gw[i] = icw[i];   // borrow gw
    if (tid < HD) sm.cb[tid] = icb[tid];                          // borrow cb
    __syncthreads();

    // ---- x0e: input conv on rows [r0-8, r0+9] ----
    for (int i = tid; i < HD*X0_R*32; i += NTHR) {
        int ci = i & 31, rr = (i >> 5) % X0_R, oc = i / (32*X0_R);
        int row = r0 - 8 + rr, col = ci - 2;
        float v = 0.0f;
        if (row >= 0 && row < HH && col >= 0 && col < WW) {
            float acc = sm.cb[oc];
            for (int ic = 0; ic < 3; ++ic)
                #pragma unroll
                for (int dy = 0; dy < 3; ++dy)
                    #pragma unroll
                    for (int dx = 0; dx < 3; ++dx)
                        acc += sm.u.s_in[ic][rr+dy][ci-1+dx]
                             * sm.gw[((oc*3 + ic)*3 + dy)*3 + dx];
            v = acc;
        }
        x0e[(oc*X0_R + rr)*32 + ci] = v;
    }
    __syncthreads();

    // ---- h00: sweep-0 node 0 (h=0, td = bias reshape), rows [r0-6, r0+7] ----
    stage_node(sm, tid, 0, gates_w, gates_b, can_w, can_b);
    {
        int a = r0 - 6;
        cell_chunk<6>(sm, tid, bi, a,     x0e, r0-8, X0_R, 1.0f, nullptr,0,0,nullptr, td_b0, nullptr, h00e, a, H00_R, nullptr);
        cell_chunk<6>(sm, tid, bi, a+6,   x0e, r0-8, X0_R, 1.0f, nullptr,0,0,nullptr, td_b0, nullptr, h00e, a, H00_R, nullptr);
        cell_chunk<2>(sm, tid, bi, a+12,  x0e, r0-8, X0_R, 1.0f, nullptr,0,0,nullptr, td_b0, nullptr, h00e, a, H00_R, nullptr);
    }

    // ---- fallback: real td projections (h01/h02 constants nonzero) ----
    if (f0 | f1) {
        if (f0) {
            for (int j = blk*NTHR + tid; j < FEAT2; j += NBLK*NTHR) {
                float s = td_b0[j];
                const float* wr = td_w0 + (size_t)j * FEAT;
                for (int c = 0; c < HD; ++c) {
                    float hcv = sm.hc1[c];
                    if (hcv != 0.0f) {
                        float ss = 0.0f;
                        for (int p = 0; p < SP; ++p) ss += wr[c*SP + p];
                        s += 0.6f * hcv * ss;
                    }
                }
                td0c[j] = s;
            }
        }
        if (f1) {
            for (int j = blk*NTHR + tid; j < FEAT2; j += NBLK*NTHR) {
                float s = td_b1[j];
                const float* wr = td_w1 + (size_t)j * FEAT;
                for (int c = 0; c < HD; ++c) {
                    float hcv = sm.hc2[c];
                    if (hcv != 0.0f) {
                        float ss = 0.0f;
                        for (int p = 0; p < SP; ++p) ss += wr[c*SP + p];
                        s += 0.5f * hcv * ss;
                    }
                }
                td1c[j] = s;
            }
        }
        gbar(arrive, release, blk, 1u);   // uniform branch: all blocks take it
    }
    const float* td0v = f0 ? td0c : td_b0;
    const float* td1v = f1 ? td1c : td_b1;

    // ---- h10: sweep-1 node 0 (weights resident), rows [r0-4, r0+5] ----
    {
        int a = r0 - 4;
        cell_chunk<6>(sm, tid, bi, a,    x0e, r0-8, X0_R, 1.0f, h00e, r0-6, H00_R, nullptr, td0v, nullptr, h10e, a, H10_R, nullptr);
        cell_chunk<4>(sm, tid, bi, a+6,  x0e, r0-8, X0_R, 1.0f, h00e, r0-6, H00_R, nullptr, td0v, nullptr, h10e, a, H10_R, nullptr);
    }

    // ---- h11: sweep-1 node 1 (x=0.8*h10, h=h01 const), rows [r0-2, r0+3] ----
    stage_node(sm, tid, 1, gates_w, gates_b, can_w, can_b);
    cell_chunk<6>(sm, tid, bi, r0-2, h10e, r0-4, H10_R, 0.8f, nullptr,0,0, sm.hc1, td1v, nullptr, h11e, r0-2, H11_R, nullptr);

    // ---- h12: sweep-1 node 2 (x=0.7*h11, h=h02 const, td external), rows [r0, r0+1] ----
    stage_node(sm, tid, 2, gates_w, gates_b, can_w, can_b);
    cell_chunk<2>(sm, tid, bi, r0, h11e, r0-2, H11_R, 0.7f, nullptr,0,0, sm.hc2, nullptr, topdown + (size_t)bi*FEAT2, nullptr, 0, 0, h12g);
}

__global__ __launch_bounds__(256)
void fc1_kernel(const float* __restrict__ in, const float* __restrict__ w,
                const float* __restrict__ b, float* __restrict__ out) {
    int j    = blockIdx.x;          // 0..99
    int wave = threadIdx.x >> 6;
    int lane = threadIdx.x & 63;
    float acc[4] = {0.f, 0.f, 0.f, 0.f};
    const float* wr = w + (size_t)j * FEAT;
    for (int k = lane; k < FEAT; k += 64) {
        float wv = wr[k];
        #pragma unroll
        for (int q = 0; q < 4; ++q) {
            float v = in[(size_t)(wave*4+q)*FEAT + k];
            acc[q] += fmaxf(v, 0.0f) * wv;
        }
    }
    #pragma unroll
    for (int off = 32; off > 0; off >>= 1)
        #pragma unroll
        for (int q = 0; q < 4; ++q)
            acc[q] += __shfl_down(acc[q], off);
    if (lane == 0) {
        #pragma unroll
        for (int q = 0; q < 4; ++q)
            out[(size_t)(wave*4+q)*100 + j] = acc[q] + b[j];
    }
}

__global__ __launch_bounds__(256)
void fc2_kernel(const float* __restrict__ p1, const float* __restrict__ w,
                const float* __restrict__ b, float* __restrict__ out) {
    int t = threadIdx.x;
    if (t >= BB*10) return;
    int bi = t / 10, j = t % 10;
    float acc = b[j];
    for (int k = 0; k < 100; ++k)
        acc += fmaxf(p1[bi*100 + k], 0.0f) * w[j*100 + k];
    out[bi*10 + j] = acc;
}

extern "C" void kernel_launch(void* const* d_in, const int* in_sizes, int n_in,
                              void* d_out, int out_size, void* d_ws, size_t ws_size,
                              hipStream_t stream) {
    const float* input_tensor = (const float*)d_in[0];
    const float* topdown      = (const float*)d_in[1];
    const float* icw  = (const float*)d_in[2];
    const float* icb  = (const float*)d_in[3];
    const float* gates_w = (const float*)d_in[4];
    const float* gates_b = (const float*)d_in[5];
    const float* can_w   = (const float*)d_in[6];
    const float* can_b   = (const float*)d_in[7];
    const float* td_w0 = (const float*)d_in[8];
    const float* td_b0 = (const float*)d_in[9];
    const float* td_w1 = (const float*)d_in[10];
    const float* td_b1 = (const float*)d_in[11];
    const float* fc1_w = (const float*)d_in[12];
    const float* fc1_b = (const float*)d_in[13];
    const float* fc2_w = (const float*)d_in[14];
    const float* fc2_b = (const float*)d_in[15];
    float* out = (float*)d_out;

    float* ws   = (float*)d_ws;
    float* h12g = ws;                       // 100352 f
    float* p1   = h12g + BB*HD*SP;          // 1600 f
    float* td0c = p1 + BB*100;              // 12544 f
    float* td1c = td0c + FEAT2;             // 12544 f
    float* slabs = (float*)((char*)d_ws + (1u << 20));       // 224 x 48 KB
    unsigned* arrive  = (unsigned*)((char*)d_ws + (16u << 20));
    unsigned* release = arrive + NBLK*16;

    init_kernel<<<1, 256, 0, stream>>>(arrive, release);
    mega_kernel<<<NBLK, NTHR, 0, stream>>>(
        input_tensor, topdown, icw, icb, gates_w, gates_b, can_w, can_b,
        td_w0, td_b0, td_w1, td_b1,
        h12g, slabs, td0c, td1c, arrive, release);
    fc1_kernel<<<100, 256, 0, stream>>>(h12g, fc1_w, fc1_b, p1);
    fc2_kernel<<<1, 256, 0, stream>>>(p1, fc2_w, fc2_b, out);
}

// Round 9
// 129.688 us; speedup vs baseline: 3.6527x; 1.6036x over previous
//
#include <hip/hip_runtime.h>
#include <cstddef>

#define HD 8
#define C2 16
#define HH 28
#define WW 28
#define BB 16
#define SP (HH*WW)           // 784
#define FEAT (HD*SP)         // 6272
#define FEAT2 (C2*SP)        // 12544

#define TILE_ROWS 2
#define NT (HH/TILE_ROWS)    // 14
#define NBLK (BB*NT)         // 224 blocks, one per (batch, row-tile)
#define NTHR 1024            // 16 waves -> 4 waves/SIMD

// LDS slab row extents (all rows relative bases tied to r0)
#define X0_R 18   // x0  rows [r0-8, r0+9]
#define H00_R 14  // h00 rows [r0-6, r0+7]
#define H10_R 10  // h10 rows [r0-4, r0+5]
#define H11_R 6   // h11 rows [r0-2, r0+3]

__device__ __forceinline__ float sigf(float x) { return 1.0f / (1.0f + expf(-x)); }

struct SM {
    float gw[C2*C2*9];                 // current node's gate weights (r=oc0..7, u=oc8..15)
    float cw[HD*C2*9];
    float gb[C2];
    float cb[HD];
    float hc1[HD];
    float hc2[HD];
    float comb[C2][18][32];            // A-phase output, rows [ca-2, ca+M+1], max M=14
    union {
        float rh[HD][16][32];          // B-phase output, rows [ca-1, ca+M]
        float s_in[3][TILE_ROWS+18][32]; // raw input rows r0-9..r0+10 (staging only)
    } u;
    float x0e[HD][X0_R][32];
    float h00e[HD][H00_R][32];
    float h10e[HD][H10_R][32];
    float h11e[HD][H11_R][32];
};  // ~114 KB

// Grid barrier (FALLBACK PATH ONLY — never executed when sweep-0 node1/2 constants are 0).
__device__ __forceinline__ void gbar(unsigned* arrive, unsigned* release,
                                     int blk, unsigned ep) {
    __syncthreads();
    __threadfence();
    if (threadIdx.x == 0)
        __hip_atomic_store(&arrive[(size_t)blk * 16], ep,
                           __ATOMIC_RELEASE, __HIP_MEMORY_SCOPE_AGENT);
    if (blk == 0) {
        int t = threadIdx.x;
        if (t < NBLK) {
            while (__hip_atomic_load(&arrive[(size_t)t * 16],
                                     __ATOMIC_RELAXED, __HIP_MEMORY_SCOPE_AGENT) < ep)
                __builtin_amdgcn_s_sleep(32);
        }
        __syncthreads();
        if (t < NBLK)
            __hip_atomic_store(&release[(size_t)t * 16], ep,
                               __ATOMIC_RELEASE, __HIP_MEMORY_SCOPE_AGENT);
    } else {
        if (threadIdx.x == 0) {
            while (__hip_atomic_load(&release[(size_t)blk * 16],
                                     __ATOMIC_RELAXED, __HIP_MEMORY_SCOPE_AGENT) < ep)
                __builtin_amdgcn_s_sleep(32);
        }
    }
    __threadfence();
    __syncthreads();
}

__device__ __forceinline__ void stage_node(SM& sm, int tid, int n,
                           const float* gates_w, const float* gates_b,
                           const float* can_w, const float* can_b) {
    for (int i = tid; i < C2*C2*9; i += NTHR) sm.gw[i] = gates_w[n*C2*C2*9 + i];
    for (int i = tid; i < HD*C2*9; i += NTHR) sm.cw[i] = can_w[n*HD*C2*9 + i];
    if (tid < C2) sm.gb[tid] = gates_b[n*C2 + tid];
    if (tid < HD) sm.cb[tid] = can_b[n*HD + tid];
    // consumer cell's first __syncthreads covers these writes
}

template<int XS>
__device__ __forceinline__ float xval(SM& sm, int c, int ridx, int ci) {
    if constexpr (XS == 0) return sm.x0e[c][ridx][ci];
    else if constexpr (XS == 1) return sm.h10e[c][ridx][ci];
    else return sm.h11e[c][ridx][ci];
}

// One full ConvGRU cell, entirely in LDS.
// M compile-time; XS: x-source slab (0=x0e,1=h10e,2=h11e); HS: h-source
// (0=zero, 1=h00e, 2=hc1, 3=hc2); OS: output (0=h00e,1=h10e,2=h11e,3=global h12g).
// Zero-elision: HS==0 => comb[8..15]==0 and r*h==0 -> skip B, 8-channel convs.
template<int M, int XS, int HS, int OS>
__device__ void cell(SM& sm, int tid, int bi, int r0, float xs,
                     const float* __restrict__ td, float* __restrict__ h12g) {
    constexpr int R1 = M + 4, R2 = M + 2;
    constexpr int NIC = (HS == 0) ? HD : C2;      // live input channels
    const int ca    = (OS == 0) ? r0-6 : (OS == 1) ? r0-4 : (OS == 2) ? r0-2 : r0;
    const int xbase = (XS == 0) ? r0-8 : (XS == 1) ? r0-4 : r0-2;
    const int hbase = r0 - 6;                      // only for HS==1

    // ---- A: comb[c] = (c<8 ? xs*x : h) * sig(td), rows [ca-2, ca+M+1] ----
    for (int i = tid; i < NIC*R1*32; i += NTHR) {
        int ci = i & 31, rr = (i >> 5) % R1, c = i / (32*R1);
        int row = ca - 2 + rr, col = ci - 2;
        float v = 0.0f;
        if (row >= 0 && row < HH && col >= 0 && col < WW) {
            float base;
            if (c < HD) base = xs * xval<XS>(sm, c, row - xbase, ci);
            else {
                if constexpr (HS == 1) base = sm.h00e[c-HD][row - hbase][ci];
                else if constexpr (HS == 2) base = sm.hc1[c-HD];
                else if constexpr (HS == 3) base = sm.hc2[c-HD];
                else base = 0.0f;
            }
            v = base * sigf(td[c*SP + row*WW + col]);
        }
        sm.comb[c][rr][ci] = v;
    }
    __syncthreads();

    // ---- B: rh[c] = sig(conv_r(comb)) * h, rows [ca-1, ca+M] (skip if h==0) ----
    if constexpr (HS != 0) {
        constexpr int P2 = R2 / 2;
        for (int i = tid; i < 2*P2*32; i += NTHR) {
            int ci = i & 31, pr = (i >> 5) % P2, g = i / (32*P2);
            int rr = pr*2;                          // rh rows rr, rr+1
            int col = ci - 2;
            float a[2][4];
            #pragma unroll
            for (int s2 = 0; s2 < 2; ++s2)
                #pragma unroll
                for (int o = 0; o < 4; ++o) a[s2][o] = sm.gb[g*4+o];
            bool colok = (col >= 0 && col < WW);
            if (colok) {
                for (int ic = 0; ic < NIC; ++ic) {
                    float cv[4][3];
                    #pragma unroll
                    for (int dy = 0; dy < 4; ++dy)
                        #pragma unroll
                        for (int dx = 0; dx < 3; ++dx)
                            cv[dy][dx] = sm.comb[ic][rr+dy][ci-1+dx];
                    const float* wp = &sm.gw[(g*4*C2 + ic)*9];
                    #pragma unroll
                    for (int o = 0; o < 4; ++o)
                        #pragma unroll
                        for (int dy = 0; dy < 3; ++dy)
                            #pragma unroll
                            for (int dx = 0; dx < 3; ++dx) {
                                float w = wp[o*C2*9 + dy*3+dx];
                                a[0][o] += cv[dy][dx]   * w;
                                a[1][o] += cv[dy+1][dx] * w;
                            }
                }
            }
            #pragma unroll
            for (int s2 = 0; s2 < 2; ++s2) {
                int row = ca - 1 + rr + s2;
                bool inb = colok && row >= 0 && row < HH;
                #pragma unroll
                for (int o = 0; o < 4; ++o) {
                    int c = g*4 + o;
                    float v = 0.0f;
                    if (inb) {
                        float hv;
                        if constexpr (HS == 1) hv = sm.h00e[c][row - hbase][ci];
                        else if constexpr (HS == 2) hv = sm.hc1[c];
                        else hv = sm.hc2[c];
                        v = sigf(a[s2][o]) * hv;
                    }
                    sm.u.rh[c][rr + s2][ci] = v;
                }
            }
        }
        __syncthreads();
    }

    // ---- C: u-gate + cand + blend, output rows [ca, ca+M-1], row-pairs ----
    {
        constexpr int PM = M / 2;
        for (int i = tid; i < 2*PM*32; i += NTHR) {
            int ci = i & 31, pr = (i >> 5) % PM, g = i / (32*PM);
            int rr = pr*2;                          // output rows ca+rr, ca+rr+1
            int col = ci - 2;
            float ua[2][4], cca[2][4];
            #pragma unroll
            for (int s2 = 0; s2 < 2; ++s2)
                #pragma unroll
                for (int o = 0; o < 4; ++o) {
                    ua[s2][o]  = sm.gb[HD + g*4 + o];
                    cca[s2][o] = sm.cb[g*4 + o];
                }
            bool colok = (col >= 0 && col < WW);
            if (colok) {
                for (int ic = 0; ic < NIC; ++ic) {
                    float cv[4][3], civ[4][3];
                    #pragma unroll
                    for (int dy = 0; dy < 4; ++dy)
                        #pragma unroll
                        for (int dx = 0; dx < 3; ++dx) {
                            cv[dy][dx] = sm.comb[ic][rr+1+dy][ci-1+dx];
                            if (ic < HD)
                                civ[dy][dx] = xs * xval<XS>(sm, ic, (ca-1+rr+dy) - xbase, ci-1+dx);
                            else
                                civ[dy][dx] = sm.u.rh[ic-HD][rr+dy][ci-1+dx];
                        }
                    const float* uwp = &sm.gw[((HD + g*4)*C2 + ic)*9];
                    const float* cwp = &sm.cw[((g*4)*C2 + ic)*9];
                    #pragma unroll
                    for (int o = 0; o < 4; ++o)
                        #pragma unroll
                        for (int dy = 0; dy < 3; ++dy)
                            #pragma unroll
                            for (int dx = 0; dx < 3; ++dx) {
                                float uw = uwp[o*C2*9 + dy*3+dx];
                                float cw = cwp[o*C2*9 + dy*3+dx];
                                ua[0][o]  += cv[dy][dx]    * uw;
                                ua[1][o]  += cv[dy+1][dx]  * uw;
                                cca[0][o] += civ[dy][dx]   * cw;
                                cca[1][o] += civ[dy+1][dx] * cw;
                            }
                }
            }
            #pragma unroll
            for (int s2 = 0; s2 < 2; ++s2) {
                int row = ca + rr + s2;
                bool inb = colok && row >= 0 && row < HH;
                #pragma unroll
                for (int o = 0; o < 4; ++o) {
                    int c = g*4 + o;
                    float outv = 0.0f;
                    if (inb) {
                        float uu = sigf(ua[s2][o]);
                        float cand = tanhf(cca[s2][o]);
                        float hv;
                        if constexpr (HS == 1) hv = sm.h00e[c][row - hbase][ci];
                        else if constexpr (HS == 2) hv = sm.hc1[c];
                        else if constexpr (HS == 3) hv = sm.hc2[c];
                        else hv = 0.0f;
                        outv = (1.0f - uu) * hv + uu * cand;
                    }
                    if constexpr (OS == 0) sm.h00e[c][row - (r0-6)][ci] = outv;
                    else if constexpr (OS == 1) sm.h10e[c][row - (r0-4)][ci] = outv;
                    else if constexpr (OS == 2) sm.h11e[c][row - (r0-2)][ci] = outv;
                    else {
                        if (inb)
                            h12g[((size_t)bi*HD + c)*SP + row*WW + col] = outv;
                    }
                }
            }
        }
        __syncthreads();
    }
}

__global__ void init_kernel(unsigned* arrive, unsigned* release) {
    int t = threadIdx.x;
    for (int i = t; i < NBLK*16; i += 256) { arrive[i] = 0u; release[i] = 0u; }
}

__global__ __launch_bounds__(NTHR)
void mega_kernel(const float* __restrict__ input_tensor, const float* __restrict__ topdown,
                 const float* __restrict__ icw, const float* __restrict__ icb,
                 const float* __restrict__ gates_w, const float* __restrict__ gates_b,
                 const float* __restrict__ can_w, const float* __restrict__ can_b,
                 const float* __restrict__ td_w0, const float* __restrict__ td_b0,
                 const float* __restrict__ td_w1, const float* __restrict__ td_b1,
                 float* __restrict__ h12g,
                 float* __restrict__ td0c, float* __restrict__ td1c,
                 unsigned* arrive, unsigned* release)
{
    const int tid = threadIdx.x;
    const int blk = blockIdx.x;
    const int bi  = blk / NT;
    const int r0  = (blk % NT) * TILE_ROWS;

    __shared__ SM sm;

    // Sweep-0 node1/2 outputs are per-channel constants (x=0,h=0 => comb==0).
    if (tid < HD) {
        sm.hc1[tid] = sigf(gates_b[1*C2 + HD + tid]) * tanhf(can_b[1*HD + tid]);
        sm.hc2[tid] = sigf(gates_b[2*C2 + HD + tid]) * tanhf(can_b[2*HD + tid]);
    }
    bool f0 = false, f1 = false;
    for (int c = 0; c < HD; ++c) {
        f0 |= (sigf(gates_b[1*C2 + HD + c]) * tanhf(can_b[1*HD + c])) != 0.0f;
        f1 |= (sigf(gates_b[2*C2 + HD + c]) * tanhf(can_b[2*HD + c])) != 0.0f;
    }

    // ---- stage raw input tile (rows r0-9..r0+10) + input-conv weights ----
    for (int i = tid; i < 3*(TILE_ROWS+18)*32; i += NTHR) {
        int ci = i & 31, rr = (i >> 5) % (TILE_ROWS+18), c = i / (32*(TILE_ROWS+18));
        int row = r0 - 9 + rr, col = ci - 2;
        float v = 0.0f;
        if (row >= 0 && row < HH && col >= 0 && col < WW)
            v = input_tensor[((size_t)bi*3 + c)*SP + row*WW + col];
        sm.u.s_in[c][rr][ci] = v;
    }
    for (int i = tid; i < HD*3*9; i += NTHR) sm.gw[i] = icw[i];   // borrow gw
    if (tid < HD) sm.cb[tid] = icb[tid];                          // borrow cb
    __syncthreads();

    // ---- x0e: input conv on rows [r0-8, r0+9] (into LDS) ----
    for (int i = tid; i < HD*X0_R*32; i += NTHR) {
        int ci = i & 31, rr = (i >> 5) % X0_R, oc = i / (32*X0_R);
        int row = r0 - 8 + rr, col = ci - 2;
        float v = 0.0f;
        if (row >= 0 && row < HH && col >= 0 && col < WW) {
            float acc = sm.cb[oc];
            for (int ic = 0; ic < 3; ++ic)
                #pragma unroll
                for (int dy = 0; dy < 3; ++dy)
                    #pragma unroll
                    for (int dx = 0; dx < 3; ++dx)
                        acc += sm.u.s_in[ic][rr+dy][ci-1+dx]
                             * sm.gw[((oc*3 + ic)*3 + dy)*3 + dx];
            v = acc;
        }
        sm.x0e[oc][rr][ci] = v;
    }
    __syncthreads();   // also guards gw/cb re-staging below

    // ---- h00: sweep-0 node 0 (h=0 -> skip B, 8-ch convs), rows [r0-6, r0+7] ----
    stage_node(sm, tid, 0, gates_w, gates_b, can_w, can_b);
    cell<14, 0, 0, 0>(sm, tid, bi, r0, 1.0f, td_b0, nullptr);

    // ---- fallback: real td projections (h01/h02 constants nonzero) ----
    if (f0 | f1) {
        if (f0) {
            for (int j = blk*NTHR + tid; j < FEAT2; j += NBLK*NTHR) {
                float s = td_b0[j];
                const float* wr = td_w0 + (size_t)j * FEAT;
                for (int c = 0; c < HD; ++c) {
                    float hcv = sm.hc1[c];
                    if (hcv != 0.0f) {
                        float ss = 0.0f;
                        for (int p = 0; p < SP; ++p) ss += wr[c*SP + p];
                        s += 0.6f * hcv * ss;
                    }
                }
                td0c[j] = s;
            }
        }
        if (f1) {
            for (int j = blk*NTHR + tid; j < FEAT2; j += NBLK*NTHR) {
                float s = td_b1[j];
                const float* wr = td_w1 + (size_t)j * FEAT;
                for (int c = 0; c < HD; ++c) {
                    float hcv = sm.hc2[c];
                    if (hcv != 0.0f) {
                        float ss = 0.0f;
                        for (int p = 0; p < SP; ++p) ss += wr[c*SP + p];
                        s += 0.5f * hcv * ss;
                    }
                }
                td1c[j] = s;
            }
        }
        gbar(arrive, release, blk, 1u);   // uniform branch: all blocks take it
    }
    const float* td0v = f0 ? td0c : td_b0;
    const float* td1v = f1 ? td1c : td_b1;

    // ---- h10: sweep-1 node 0 (weights resident), rows [r0-4, r0+5] ----
    cell<10, 0, 1, 1>(sm, tid, bi, r0, 1.0f, td0v, nullptr);

    // ---- h11: sweep-1 node 1 (x=0.8*h10, h=hc1), rows [r0-2, r0+3] ----
    stage_node(sm, tid, 1, gates_w, gates_b, can_w, can_b);
    cell<6, 1, 2, 2>(sm, tid, bi, r0, 0.8f, td1v, nullptr);

    // ---- h12: sweep-1 node 2 (x=0.7*h11, h=hc2, td external), rows [r0, r0+1] ----
    stage_node(sm, tid, 2, gates_w, gates_b, can_w, can_b);
    cell<2, 2, 3, 3>(sm, tid, bi, r0, 0.7f, topdown + (size_t)bi*FEAT2, h12g);
}

__global__ __launch_bounds__(256)
void fc1_kernel(const float* __restrict__ in, const float* __restrict__ w,
                const float* __restrict__ b, float* __restrict__ out) {
    int j    = blockIdx.x;          // 0..99
    int wave = threadIdx.x >> 6;
    int lane = threadIdx.x & 63;
    float acc[4] = {0.f, 0.f, 0.f, 0.f};
    const float* wr = w + (size_t)j * FEAT;
    for (int k = lane; k < FEAT; k += 64) {
        float wv = wr[k];
        #pragma unroll
        for (int q = 0; q < 4; ++q) {
            float v = in[(size_t)(wave*4+q)*FEAT + k];
            acc[q] += fmaxf(v, 0.0f) * wv;
        }
    }
    #pragma unroll
    for (int off = 32; off > 0; off >>= 1)
        #pragma unroll
        for (int q = 0; q < 4; ++q)
            acc[q] += __shfl_down(acc[q], off);
    if (lane == 0) {
        #pragma unroll
        for (int q = 0; q < 4; ++q)
            out[(size_t)(wave*4+q)*100 + j] = acc[q] + b[j];
    }
}

__global__ __launch_bounds__(256)
void fc2_kernel(const float* __restrict__ p1, const float* __restrict__ w,
                const float* __restrict__ b, float* __restrict__ out) {
    int t = threadIdx.x;
    if (t >= BB*10) return;
    int bi = t / 10, j = t % 10;
    float acc = b[j];
    for (int k = 0; k < 100; ++k)
        acc += fmaxf(p1[bi*100 + k], 0.0f) * w[j*100 + k];
    out[bi*10 + j] = acc;
}

extern "C" void kernel_launch(void* const* d_in, const int* in_sizes, int n_in,
                              void* d_out, int out_size, void* d_ws, size_t ws_size,
                              hipStream_t stream) {
    const float* input_tensor = (const float*)d_in[0];
    const float* topdown      = (const float*)d_in[1];
    const float* icw  = (const float*)d_in[2];
    const float* icb  = (const float*)d_in[3];
    const float* gates_w = (const float*)d_in[4];
    const float* gates_b = (const float*)d_in[5];
    const float* can_w   = (const float*)d_in[6];
    const float* can_b   = (const float*)d_in[7];
    const float* td_w0 = (const float*)d_in[8];
    const float* td_b0 = (const float*)d_in[9];
    const float* td_w1 = (const float*)d_in[10];
    const float* td_b1 = (const float*)d_in[11];
    const float* fc1_w = (const float*)d_in[12];
    const float* fc1_b = (const float*)d_in[13];
    const float* fc2_w = (const float*)d_in[14];
    const float* fc2_b = (const float*)d_in[15];
    float* out = (float*)d_out;

    float* ws   = (float*)d_ws;
    float* h12g = ws;                       // 100352 f
    float* p1   = h12g + BB*HD*SP;          // 1600 f
    float* td0c = p1 + BB*100;              // 12544 f
    float* td1c = td0c + FEAT2;             // 12544 f
    unsigned* arrive  = (unsigned*)((char*)d_ws + (16u << 20));
    unsigned* release = arrive + NBLK*16;

    init_kernel<<<1, 256, 0, stream>>>(arrive, release);
    mega_kernel<<<NBLK, NTHR, 0, stream>>>(
        input_tensor, topdown, icw, icb, gates_w, gates_b, can_w, can_b,
        td_w0, td_b0, td_w1, td_b1,
        h12g, td0c, td1c, arrive, release);
    fc1_kernel<<<100, 256, 0, stream>>>(h12g, fc1_w, fc1_b, p1);
    fc2_kernel<<<1, 256, 0, stream>>>(p1, fc2_w, fc2_b, out);
}